// Round 15
// baseline (417.553 us; speedup 1.0000x reference)
//
#include <hip/hip_runtime.h>

#define N_PTS 8192
#define R2F 0.015625f   // R*R, exactly representable

// ---------------- g = x @ W1a (NO bias; R16 chain verbatim, 32-row tiles) ---
__global__ __launch_bounds__(256) void k_g(const float* __restrict__ x,
                                           const float* __restrict__ W1,
                                           float* __restrict__ g) {
    __shared__ float xs[32][68];
    __shared__ float ws_[64][64];
    const int t = threadIdx.x;
    const int r0 = blockIdx.x * 32;
    for (int v = t; v < 1024; v += 256)
        ((float4*)&ws_[0][0])[v] = ((const float4*)W1)[v];   // W1 rows 0..63
    for (int v = t; v < 512; v += 256) {
        const int n = v >> 4, c4 = (v & 15) * 4;
        *(float4*)&xs[n][c4] = *(const float4*)&x[(r0 + n) * 64 + c4];
    }
    __syncthreads();
    const int c0 = (t & 15) * 4, n0 = (t >> 4) * 2;
    float acc[2][4];
    #pragma unroll
    for (int ni = 0; ni < 2; ++ni)
        #pragma unroll
        for (int ci = 0; ci < 4; ++ci) acc[ni][ci] = 0.0f;
    #pragma unroll
    for (int kb4 = 0; kb4 < 16; ++kb4) {
        float4 av[2], wv[4];
        #pragma unroll
        for (int ni = 0; ni < 2; ++ni)
            av[ni] = *(const float4*)&xs[n0 + ni][kb4 * 4];
        #pragma unroll
        for (int ki = 0; ki < 4; ++ki)
            wv[ki] = *(const float4*)&ws_[kb4 * 4 + ki][c0];
        #pragma unroll
        for (int ki = 0; ki < 4; ++ki) {           // k = 4*kb4 + ki, ascending
            #pragma unroll
            for (int ni = 0; ni < 2; ++ni) {
                const float a = (&av[ni].x)[ki];
                acc[ni][0] = __fmaf_rn(a, wv[ki].x, acc[ni][0]);
                acc[ni][1] = __fmaf_rn(a, wv[ki].y, acc[ni][1]);
                acc[ni][2] = __fmaf_rn(a, wv[ki].z, acc[ni][2]);
                acc[ni][3] = __fmaf_rn(a, wv[ki].w, acc[ni][3]);
            }
        }
    }
    #pragma unroll
    for (int ni = 0; ni < 2; ++ni)
        *(float4*)&g[(r0 + n0 + ni) * 64 + c0] =
            make_float4(acc[ni][0], acc[ni][1], acc[ni][2], acc[ni][3]);
}

// Bit-exact d2 key: shared by phase 1 and the rare rescan path. Identical
// intrinsic DAG (__fmul/__fadd/__fmaf/__fsub _rn) -> identical bits at both
// call sites (IEEE determinism; no reassociation possible on intrinsics).
__device__ __forceinline__ unsigned d2key(const float* __restrict__ pos, int j,
                                          float xi, float yi, float zi,
                                          float sqi) {
    const float xj = pos[j * 3 + 0], yj = pos[j * 3 + 1], zj = pos[j * 3 + 2];
    const float sqj = __fadd_rn(__fadd_rn(__fmul_rn(xj, xj), __fmul_rn(yj, yj)),
                                __fmul_rn(zj, zj));
    const float dot = __fmaf_rn(zi, zj, __fmaf_rn(yi, yj, __fmul_rn(xi, xj)));
    const float d2  = __fsub_rn(__fadd_rn(sqi, sqj), __fmul_rn(2.0f, dot));
    unsigned b = __float_as_uint(d2);
    return (b & 0x80000000u) ? ~b : (b | 0x80000000u);  // monotone total order
}

// ---------------- k_sel: neighbor selection, 8-way j-split ------------------
// R14: VGPR=24 (no spill ever) refuted the R11 spill theory; k_sel ~155us is
// the serial pop chain: ~18.7 rounds/wave x 7-deep dependent bpermute chain.
// Fix: split j-space over EIGHT waves (1024 pts each) -> within-R per eighth
// ~8.4 -> ~9.4 rounds (/2); phase-1 16 iters (/2); merge generalizes 4->8
// lists (pad ids widened to 9 bits, same uniqueness argument as the R9 fix).
// Final broadcast via readfirstlane (all lanes active) drops 1 of 7 LDS ops.
// (512,4) caps VGPR at 32 under BOTH launch_bounds semantics; need ~26 -> safe.
__global__ __launch_bounds__(512, 4) void k_sel(const float* __restrict__ pos,
                                                float* __restrict__ out) {
    __shared__ unsigned mb[8][64];
    __shared__ unsigned mj[8][64];

    const int t    = threadIdx.x;    // 0..511
    const int lane = t & 63;
    const int w    = t >> 6;         // wave id 0..7; owns j in [1024w, 1024w+1024)
    const int qb   = w << 10;
    const int i    = blockIdx.x;

    const float xi = pos[i * 3 + 0], yi = pos[i * 3 + 1], zi = pos[i * 3 + 2];
    const float sqi = __fadd_rn(__fadd_rn(__fmul_rn(xi, xi), __fmul_rn(yi, yi)),
                                __fmul_rn(zi, zi));

    // ---- phase 1: d2 keys over 16 candidates/lane; track FOUR smallest ----
    // Strict '<' + ascending j => on b-tie the incumbent (smaller j) wins.
    unsigned m1b = 0xFFFFFFFFu, m2b = 0xFFFFFFFFu,
             m3b = 0xFFFFFFFFu, m4b = 0xFFFFFFFFu;
    int      m1j = 0x7FFFFFFF,  m2j = 0x7FFFFFFF,
             m3j = 0x7FFFFFFF,  m4j = 0x7FFFFFFF;
    #pragma unroll
    for (int k = 0; k < 16; ++k) {
        const int j = qb + lane + (k << 6);
        const unsigned b = d2key(pos, j, xi, yi, zi, sqi);
        if (b < m1b) {
            m4b = m3b; m4j = m3j; m3b = m2b; m3j = m2j;
            m2b = m1b; m2j = m1j; m1b = b;   m1j = j;
        } else if (b < m2b) {
            m4b = m3b; m4j = m3j; m3b = m2b; m3j = m2j;
            m2b = b;   m2j = j;
        } else if (b < m3b) {
            m4b = m3b; m4j = m3j; m3b = b;   m3j = j;
        } else if (b < m4b) {
            m4b = b;   m4j = j;
        }
    }

    // unique ascending pads (9-bit id < 512): no rank collisions in the merge
    mb[w][lane] = 0xFFFFFFFFu;
    mj[w][lane] = 0xFFFFFE00u | (unsigned)((w << 6) | lane);

    // ---- pops with early exit; lazy lane-min: m1->m2->m3->m4->rescan ----
    unsigned removed = 0u;           // bits [0,16)
    int      level = 0;
    unsigned lb = m1b;
    int      lj = m1j;
    for (int s = 0; s < 64; ++s) {
        unsigned rb = lb;
        int      rj = lj;
        #pragma unroll
        for (int off = 32; off > 0; off >>= 1) {
            const unsigned ob = (unsigned)__shfl_down((int)rb, off);
            const int      oj = __shfl_down(rj, off);
            if (ob < rb || (ob == rb && oj < rj)) { rb = ob; rj = oj; }
        }
        // lane 0 holds the wave min; all 64 lanes active -> readfirstlane
        const unsigned wb = (unsigned)__builtin_amdgcn_readfirstlane((int)rb);
        const int      wj = __builtin_amdgcn_readfirstlane(rj);
        const unsigned db = (wb & 0x80000000u) ? (wb ^ 0x80000000u) : ~wb;
        if (!(__uint_as_float(db) <= R2F)) break;   // wave-uniform; pops ascend
        if (lane == 0) { mb[w][s] = wb; mj[w][s] = (unsigned)wj; }
        if (lb == wb && lj == wj) {                 // unique owner lane
            removed |= 1u << ((wj - qb - lane) >> 6);
            ++level;
            if      (level == 1) { lb = m2b; lj = m2j; }
            else if (level == 2) { lb = m3b; lj = m3j; }
            else if (level == 3) { lb = m4b; lj = m4j; }
            else {                                  // rare: recompute rescan
                lb = 0xFFFFFFFFu; lj = 0x7FFFFFFF;
                #pragma unroll 4
                for (int k = 0; k < 16; ++k) {
                    if (!(removed & (1u << k))) {
                        const int jr = qb + lane + (k << 6);
                        const unsigned b = d2key(pos, jr, xi, yi, zi, sqi);
                        if (b < lb) { lb = b; lj = jr; }  // j asc: ties keep incumbent
                    }
                }
            }
        }
    }
    __syncthreads();

    {   // merge: exact global top-64 by (b, j) via parallel rank over 8 lists
        const int p = lane;
        const unsigned be = mb[w][p];
        const unsigned je = mj[w][p];
        int rank = p;
        #pragma unroll
        for (int d = 1; d < 8; ++d) {
            const int wp = (w + d) & 7;
            int lo = 0;
            #pragma unroll
            for (int st = 32; st > 0; st >>= 1) {
                const int idx = lo + st - 1;
                const unsigned ob = mb[wp][idx];
                const unsigned oj = mj[wp][idx];
                if (ob < be || (ob == be && oj < je)) lo += st;
            }
            {
                const unsigned ob = mb[wp][lo];
                const unsigned oj = mj[wp][lo];
                if (ob < be || (ob == be && oj < je)) lo += 1;
            }
            rank += lo;
        }
        if (rank < 64) {
            const unsigned db = (be & 0x80000000u) ? (be ^ 0x80000000u) : ~be;
            const bool ok = (__uint_as_float(db) <= R2F);  // pads decode NaN -> false
            ((ushort*)(out + (size_t)i * 256))[rank] =
                (ushort)((je & 8191u) | (ok ? 0x8000u : 0u));
        }
    }
}

// ---------------- k_mlp: gather + MLP + max-agg + global_nn -----------------
// Phases 2-4 byte-identical to the R10-passed kernel. R14: VGPR=40 -> 5
// waves/SIMD. (256,7) caps at 36 under both launch_bounds semantics; phase-3
// peak (acc16 + wt8 + av2 + addr) should fit -> 7 waves/SIMD. Spill tripwire:
// WRITE_SIZE >> 8 MB means the cap forced scratch -> revert next round.
__global__ __launch_bounds__(256, 7) void k_mlp(const float* __restrict__ g,
                                                const float* __restrict__ pos,
                                                const float* __restrict__ W1,
                                                const float* __restrict__ b1,
                                                const float* __restrict__ W2,
                                                const float* __restrict__ b2,
                                                const float* __restrict__ Wg,
                                                const float* __restrict__ bg,
                                                float* __restrict__ out) {
    __shared__ float gs[64][68];     // 17408 B
    __shared__ float pmw[4][128];    // 2 KB
    __shared__ float aggS[128];
    __shared__ int   selj[64];
    __shared__ int   nvalidS;

    const int t = threadIdx.x;
    const int w = t >> 6;
    const int i = blockIdx.x;

    const float xi = pos[i * 3 + 0], yi = pos[i * 3 + 1], zi = pos[i * 3 + 2];

    bool ok = false;
    if (t < 64) {   // wave 0 reads the packed selection from its own out row
        const unsigned sv = ((const ushort*)(out + (size_t)i * 256))[t];
        selj[t] = (int)(sv & 8191u);
        ok = (sv & 0x8000u) != 0u;
    }
    __syncthreads();   // selj visible to all

    // ======== gather g rows; nvalid ballot (wave 0) ========================
    for (int v = t; v < 1024; v += 256) {
        const int n = v >> 4, c4 = (v & 15) * 4;   // rows >= nvalid never used
        *(float4*)&gs[n][c4] = *(const float4*)&g[selj[n] * 64 + c4];
    }
    {
        const unsigned long long vm = __ballot(ok);
        if (t == 0) nvalidS = __popcll(vm);        // asc d2 -> popcount == prefix
    }
    __syncthreads();
    const int nvalid = nvalidS;

    // ======== phase 2: h1 = relu(g + rel @ W1b + b1), IN PLACE over gs ======
    {
        const int c0 = (t & 15) * 4, n0 = (t >> 4) * 4;
        float rr[4][3];
        #pragma unroll
        for (int ni = 0; ni < 4; ++ni) {
            const int j = selj[n0 + ni];
            rr[ni][0] = pos[j * 3 + 0] - xi;
            rr[ni][1] = pos[j * 3 + 1] - yi;
            rr[ni][2] = pos[j * 3 + 2] - zi;
        }
        float w1b[3][4], bb[4];
        #pragma unroll
        for (int ci = 0; ci < 4; ++ci) {
            w1b[0][ci] = W1[4096 + c0 + ci];
            w1b[1][ci] = W1[4160 + c0 + ci];
            w1b[2][ci] = W1[4224 + c0 + ci];
            bb[ci]     = b1[c0 + ci];
        }
        #pragma unroll
        for (int ni = 0; ni < 4; ++ni) {
            const int n = n0 + ni;
            const float4 gv = *(const float4*)&gs[n][c0];
            float4 hv;
            #pragma unroll
            for (int ci = 0; ci < 4; ++ci) {
                float a = (&gv.x)[ci];             // == full ascending-k sum
                a = __fmaf_rn(rr[ni][0], w1b[0][ci], a);
                a = __fmaf_rn(rr[ni][1], w1b[1][ci], a);
                a = __fmaf_rn(rr[ni][2], w1b[2][ci], a);
                a = fmaxf(a + bb[ci], 0.0f);
                (&hv.x)[ci] = (n < nvalid) ? a : 0.0f;
            }
            *(float4*)&gs[n][c0] = hv;             // in-place h1
        }
    }
    __syncthreads();

    // ======== phase 3: h2 = relu(h1 @ W2 + b2); masked max over n ==========
    // Channel-split (two 4-ch halves), 2-row W2 tile, float2 h1 reads; the
    // per-output FMA chain runs cc = 0..63 strictly ascending -> bit-exact.
    {
        const float (*h1)[68] = gs;
        const int c4 = (t & 15) * 4;
        const int nb = (t >> 4) * 4;
        #pragma unroll
        for (int half = 0; half < 2; ++half) {
            const int ch0 = half * 64 + c4;
            float acc[4][4];
            #pragma unroll
            for (int ni = 0; ni < 4; ++ni)
                #pragma unroll
                for (int k = 0; k < 4; ++k) acc[ni][k] = 0.0f;

            #pragma unroll 2
            for (int ccb = 0; ccb < 16; ++ccb) {
                #pragma unroll
                for (int pr = 0; pr < 2; ++pr) {   // cc = ccb*4 + pr*2 + {0,1}
                    const int cc0 = ccb * 4 + pr * 2;
                    const float4 wt0 = *(const float4*)&W2[(cc0 + 0) * 128 + ch0];
                    const float4 wt1 = *(const float4*)&W2[(cc0 + 1) * 128 + ch0];
                    #pragma unroll
                    for (int ni = 0; ni < 4; ++ni) {
                        const float2 av = *(const float2*)&h1[nb + ni][cc0];
                        acc[ni][0] = __fmaf_rn(av.x, wt0.x, acc[ni][0]);
                        acc[ni][1] = __fmaf_rn(av.x, wt0.y, acc[ni][1]);
                        acc[ni][2] = __fmaf_rn(av.x, wt0.z, acc[ni][2]);
                        acc[ni][3] = __fmaf_rn(av.x, wt0.w, acc[ni][3]);
                        acc[ni][0] = __fmaf_rn(av.y, wt1.x, acc[ni][0]);
                        acc[ni][1] = __fmaf_rn(av.y, wt1.y, acc[ni][1]);
                        acc[ni][2] = __fmaf_rn(av.y, wt1.z, acc[ni][2]);
                        acc[ni][3] = __fmaf_rn(av.y, wt1.w, acc[ni][3]);
                    }
                }
            }
            float m4v[4];
            #pragma unroll
            for (int k = 0; k < 4; ++k) {
                const float bb = b2[ch0 + k];
                float mm = 0.0f;  // relu floor; valid set nonempty (self)
                #pragma unroll
                for (int ni = 0; ni < 4; ++ni)
                    if (nb + ni < nvalid) mm = fmaxf(mm, acc[ni][k] + bb);
                m4v[k] = mm;
            }
            #pragma unroll
            for (int k = 0; k < 4; ++k) {          // exact max-reduce over n-groups
                float v = m4v[k];
                v = fmaxf(v, __shfl_down(v, 32));
                v = fmaxf(v, __shfl_down(v, 16));
                m4v[k] = v;
            }
            if ((t & 63) < 16) {
                #pragma unroll
                for (int k = 0; k < 4; ++k) pmw[w][ch0 + k] = m4v[k];
            }
        }
    }
    __syncthreads();

    if (t < 128)
        aggS[t] = fmaxf(fmaxf(pmw[0][t], pmw[1][t]),
                        fmaxf(pmw[2][t], pmw[3][t]));
    __syncthreads();

    // ======== phase 4: out[i][t] = relu(aggS . Wg[:,t] + bg[t]) ============
    {
        float acc = 0.0f;
        #pragma unroll 8
        for (int k = 0; k < 128; ++k)
            acc = __fmaf_rn(aggS[k], Wg[k * 256 + t], acc);
        out[i * 256 + t] = fmaxf(acc + bg[t], 0.0f);
    }
}

// ---------------------------------------------------------------------------
extern "C" void kernel_launch(void* const* d_in, const int* in_sizes, int n_in,
                              void* d_out, int out_size, void* d_ws, size_t ws_size,
                              hipStream_t stream) {
    const float* x   = (const float*)d_in[0];
    const float* pos = (const float*)d_in[1];
    // d_in[2] = batch (all zeros) — unused
    const float* W1 = (const float*)d_in[3];
    const float* b1 = (const float*)d_in[4];
    const float* W2 = (const float*)d_in[5];
    const float* b2 = (const float*)d_in[6];
    const float* Wg = (const float*)d_in[7];
    const float* bg = (const float*)d_in[8];
    float* out = (float*)d_out;

    float* g = (float*)d_ws;   // 8192*64 floats = 2 MB, fully written by k_g

    k_g<<<N_PTS / 32, 256, 0, stream>>>(x, W1, g);
    k_sel<<<N_PTS, 512, 0, stream>>>(pos, out);
    k_mlp<<<N_PTS, 256, 0, stream>>>(g, pos, W1, b1, W2, b2, Wg, bg, out);
}

// Round 22
// 380.400 us; speedup vs baseline: 1.0977x; 1.0977x over previous
//
#include <hip/hip_runtime.h>

#define N_PTS 8192
#define R2F 0.015625f   // R*R, exactly representable

// ---------------- g = x @ W1a (NO bias; R16 chain verbatim, 32-row tiles) ---
__global__ __launch_bounds__(256) void k_g(const float* __restrict__ x,
                                           const float* __restrict__ W1,
                                           float* __restrict__ g) {
    __shared__ float xs[32][68];
    __shared__ float ws_[64][64];
    const int t = threadIdx.x;
    const int r0 = blockIdx.x * 32;
    for (int v = t; v < 1024; v += 256)
        ((float4*)&ws_[0][0])[v] = ((const float4*)W1)[v];   // W1 rows 0..63
    for (int v = t; v < 512; v += 256) {
        const int n = v >> 4, c4 = (v & 15) * 4;
        *(float4*)&xs[n][c4] = *(const float4*)&x[(r0 + n) * 64 + c4];
    }
    __syncthreads();
    const int c0 = (t & 15) * 4, n0 = (t >> 4) * 2;
    float acc[2][4];
    #pragma unroll
    for (int ni = 0; ni < 2; ++ni)
        #pragma unroll
        for (int ci = 0; ci < 4; ++ci) acc[ni][ci] = 0.0f;
    #pragma unroll
    for (int kb4 = 0; kb4 < 16; ++kb4) {
        float4 av[2], wv[4];
        #pragma unroll
        for (int ni = 0; ni < 2; ++ni)
            av[ni] = *(const float4*)&xs[n0 + ni][kb4 * 4];
        #pragma unroll
        for (int ki = 0; ki < 4; ++ki)
            wv[ki] = *(const float4*)&ws_[kb4 * 4 + ki][c0];
        #pragma unroll
        for (int ki = 0; ki < 4; ++ki) {           // k = 4*kb4 + ki, ascending
            #pragma unroll
            for (int ni = 0; ni < 2; ++ni) {
                const float a = (&av[ni].x)[ki];
                acc[ni][0] = __fmaf_rn(a, wv[ki].x, acc[ni][0]);
                acc[ni][1] = __fmaf_rn(a, wv[ki].y, acc[ni][1]);
                acc[ni][2] = __fmaf_rn(a, wv[ki].z, acc[ni][2]);
                acc[ni][3] = __fmaf_rn(a, wv[ki].w, acc[ni][3]);
            }
        }
    }
    #pragma unroll
    for (int ni = 0; ni < 2; ++ni)
        *(float4*)&g[(r0 + n0 + ni) * 64 + c0] =
            make_float4(acc[ni][0], acc[ni][1], acc[ni][2], acc[ni][3]);
}

// Bit-exact d2 key: shared by phase 1 and the rescan path. Identical intrinsic
// DAG -> identical bits at all call sites (IEEE determinism, no reassociation).
__device__ __forceinline__ unsigned d2key(const float* __restrict__ pos, int j,
                                          float xi, float yi, float zi,
                                          float sqi) {
    const float xj = pos[j * 3 + 0], yj = pos[j * 3 + 1], zj = pos[j * 3 + 2];
    const float sqj = __fadd_rn(__fadd_rn(__fmul_rn(xj, xj), __fmul_rn(yj, yj)),
                                __fmul_rn(zj, zj));
    const float dot = __fmaf_rn(zi, zj, __fmaf_rn(yi, yj, __fmul_rn(xi, xj)));
    const float d2  = __fsub_rn(__fadd_rn(sqi, sqj), __fmul_rn(2.0f, dot));
    unsigned b = __float_as_uint(d2);
    return (b & 0x80000000u) ? ~b : (b | 0x80000000u);  // monotone total order
}

__device__ __forceinline__ bool lexlt(unsigned ab, int aj, unsigned bb, int bj) {
    return ab < bb || (ab == bb && aj < bj);
}

// ---------------- k_sel: 4-way split, POP-2 per reduce round ----------------
// R15 bracketing: 4-way = latency-bound on the pop chain (~20% VALU, 155us);
// 8-way = issue-bound on the 8-list merge (85% VALU, 201us). This keeps the
// 4-way structure (cheap 4-list merge) and pops TWO per butterfly round:
// each lane contributes its two smallest unremoved candidates; the reduce
// keeps the combined top-2. Rounds ~18.7 -> ~10.4, halving the serial term.
// Emitted pop sequence is IDENTICAL to pop-1 (global top-2 of unremoved =
// top-2 of lane-top-2s; strict-< incumbent-wins tie-break; ascending writes).
__global__ __launch_bounds__(256, 6) void k_sel(const float* __restrict__ pos,
                                                float* __restrict__ out) {
    __shared__ unsigned mb[4][64];
    __shared__ unsigned mj[4][64];

    const int t    = threadIdx.x;
    const int lane = t & 63;
    const int w    = t >> 6;         // wave id; owns quarter j in [2048w, 2048w+2048)
    const int qb   = w << 11;
    const int i    = blockIdx.x;

    const float xi = pos[i * 3 + 0], yi = pos[i * 3 + 1], zi = pos[i * 3 + 2];
    const float sqi = __fadd_rn(__fadd_rn(__fmul_rn(xi, xi), __fmul_rn(yi, yi)),
                                __fmul_rn(zi, zi));

    // ---- phase 1: d2 keys; track per-lane FOUR smallest (b, j) ----
    unsigned m1b = 0xFFFFFFFFu, m2b = 0xFFFFFFFFu,
             m3b = 0xFFFFFFFFu, m4b = 0xFFFFFFFFu;
    int      m1j = 0x7FFFFFFF,  m2j = 0x7FFFFFFF,
             m3j = 0x7FFFFFFF,  m4j = 0x7FFFFFFF;
    #pragma unroll
    for (int k = 0; k < 32; ++k) {
        const int j = qb + lane + (k << 6);
        const unsigned b = d2key(pos, j, xi, yi, zi, sqi);
        if (b < m1b) {
            m4b = m3b; m4j = m3j; m3b = m2b; m3j = m2j;
            m2b = m1b; m2j = m1j; m1b = b;   m1j = j;
        } else if (b < m2b) {
            m4b = m3b; m4j = m3j; m3b = m2b; m3j = m2j;
            m2b = b;   m2j = j;
        } else if (b < m3b) {
            m4b = m3b; m4j = m3j; m3b = b;   m3j = j;
        } else if (b < m4b) {
            m4b = b;   m4j = j;
        }
    }

    // unique ascending pads: no rank collisions in the merge (the R9 bug)
    mb[w][lane] = 0xFFFFFFFFu;
    mj[w][lane] = 0xFFFFFF00u | (unsigned)((w << 6) | lane);

    // ---- pop-2 rounds; lane candidates (c1,c2) = two smallest unremoved ----
    // level = # of this lane's candidates popped (lane pops ascend): level<=2
    // -> (m(l+1), m(l+2)); level==3 -> rescan gives (m4, 5th); level>=4 ->
    // rescan top-2. Rescan recomputes keys bit-exactly over the removed mask.
    unsigned removed = 0u;
    int      level = 0;
    unsigned c1b = m1b, c2b = m2b;
    int      c1j = m1j, c2j = m2j;
    int s = 0;
    while (s < 64) {
        unsigned r1b = c1b, r2b = c2b;
        int      r1j = c1j, r2j = c2j;
        #pragma unroll
        for (int off = 32; off > 0; off >>= 1) {
            const unsigned o1b = (unsigned)__shfl_down((int)r1b, off);
            const int      o1j = __shfl_down(r1j, off);
            const unsigned o2b = (unsigned)__shfl_down((int)r2b, off);
            const int      o2j = __shfl_down(r2j, off);
            if (lexlt(o1b, o1j, r1b, r1j)) {
                // top2 of {o1<=o2} U {r1<=r2} with o1 smallest: {o1, min(r1,o2)}
                if (lexlt(o2b, o2j, r1b, r1j)) { r2b = o2b; r2j = o2j; }
                else                           { r2b = r1b; r2j = r1j; }
                r1b = o1b; r1j = o1j;
            } else {
                // r1 smallest: {r1, min(r2,o1)}
                if (lexlt(o1b, o1j, r2b, r2j)) { r2b = o1b; r2j = o1j; }
            }
        }
        const unsigned w1b = (unsigned)__builtin_amdgcn_readfirstlane((int)r1b);
        const int      w1j = __builtin_amdgcn_readfirstlane(r1j);
        const unsigned w2b = (unsigned)__builtin_amdgcn_readfirstlane((int)r2b);
        const int      w2j = __builtin_amdgcn_readfirstlane(r2j);

        const unsigned d1 = (w1b & 0x80000000u) ? (w1b ^ 0x80000000u) : ~w1b;
        if (!(__uint_as_float(d1) <= R2F)) break;   // wave-uniform; pops ascend
        const unsigned d2 = (w2b & 0x80000000u) ? (w2b ^ 0x80000000u) : ~w2b;
        const bool take2 = (__uint_as_float(d2) <= R2F) && (s + 1 < 64);

        if (lane == 0) {
            mb[w][s] = w1b; mj[w][s] = (unsigned)w1j;
            if (take2) { mb[w][s + 1] = w2b; mj[w][s + 1] = (unsigned)w2j; }
        }

        int npop = 0;
        if (c1b == w1b && c1j == w1j) {             // unique owner (j distinct)
            removed |= 1u << ((c1j - qb - lane) >> 6);
            ++npop;
        }
        if (take2) {
            if (c1b == w2b && c1j == w2j) {         // c1 not popped as w1 above
                removed |= 1u << ((c1j - qb - lane) >> 6);
                ++npop;
            } else if (c2b == w2b && c2j == w2j) {  // same-lane double pop
                removed |= 1u << ((c2j - qb - lane) >> 6);
                ++npop;
            }
        }
        if (npop) {
            level += npop;
            if      (level == 1) { c1b = m2b; c1j = m2j; c2b = m3b; c2j = m3j; }
            else if (level == 2) { c1b = m3b; c1j = m3j; c2b = m4b; c2j = m4j; }
            else {                                  // rescan top-2 of unremoved
                c1b = 0xFFFFFFFFu; c1j = 0x7FFFFFFF;
                c2b = 0xFFFFFFFFu; c2j = 0x7FFFFFFF;
                #pragma unroll 4
                for (int k = 0; k < 32; ++k) {
                    if (!(removed & (1u << k))) {
                        const int jr = qb + lane + (k << 6);
                        const unsigned b = d2key(pos, jr, xi, yi, zi, sqi);
                        if (b < c1b) {              // j asc: ties keep incumbent
                            c2b = c1b; c2j = c1j; c1b = b; c1j = jr;
                        } else if (b < c2b) {
                            c2b = b; c2j = jr;
                        }
                    }
                }
            }
        }
        s += take2 ? 2 : 1;
    }
    __syncthreads();

    {   // merge: exact global top-64 by (b, j) via parallel rank (bijective)
        const int p = lane;
        const unsigned be = mb[w][p];
        const unsigned je = mj[w][p];
        int rank = p;
        #pragma unroll
        for (int d = 1; d < 4; ++d) {
            const int wp = (w + d) & 3;
            int lo = 0;
            #pragma unroll
            for (int st = 32; st > 0; st >>= 1) {
                const int idx = lo + st - 1;
                const unsigned ob = mb[wp][idx];
                const unsigned oj = mj[wp][idx];
                if (ob < be || (ob == be && oj < je)) lo += st;
            }
            {
                const unsigned ob = mb[wp][lo];
                const unsigned oj = mj[wp][lo];
                if (ob < be || (ob == be && oj < je)) lo += 1;
            }
            rank += lo;
        }
        if (rank < 64) {
            const unsigned db = (be & 0x80000000u) ? (be ^ 0x80000000u) : ~be;
            const bool ok = (__uint_as_float(db) <= R2F);  // pads decode NaN -> false
            ((ushort*)(out + (size_t)i * 256))[rank] =
                (ushort)((je & 8191u) | (ok ? 0x8000u : 0u));
        }
    }
}

// ---------------- k_mlp: gather + MLP + max-agg + global_nn -----------------
// Reverted to the R14-measured config: (256,6), VGPR 40, 194.5us, no spill.
// ((256,7)'s 36-reg cap likely spilled in R15 -- R4 failure mode.)
__global__ __launch_bounds__(256, 6) void k_mlp(const float* __restrict__ g,
                                                const float* __restrict__ pos,
                                                const float* __restrict__ W1,
                                                const float* __restrict__ b1,
                                                const float* __restrict__ W2,
                                                const float* __restrict__ b2,
                                                const float* __restrict__ Wg,
                                                const float* __restrict__ bg,
                                                float* __restrict__ out) {
    __shared__ float gs[64][68];     // 17408 B
    __shared__ float pmw[4][128];    // 2 KB
    __shared__ float aggS[128];
    __shared__ int   selj[64];
    __shared__ int   nvalidS;

    const int t = threadIdx.x;
    const int w = t >> 6;
    const int i = blockIdx.x;

    const float xi = pos[i * 3 + 0], yi = pos[i * 3 + 1], zi = pos[i * 3 + 2];

    bool ok = false;
    if (t < 64) {   // wave 0 reads the packed selection from its own out row
        const unsigned sv = ((const ushort*)(out + (size_t)i * 256))[t];
        selj[t] = (int)(sv & 8191u);
        ok = (sv & 0x8000u) != 0u;
    }
    __syncthreads();   // selj visible to all

    // ======== gather g rows; nvalid ballot (wave 0) ========================
    for (int v = t; v < 1024; v += 256) {
        const int n = v >> 4, c4 = (v & 15) * 4;   // rows >= nvalid never used
        *(float4*)&gs[n][c4] = *(const float4*)&g[selj[n] * 64 + c4];
    }
    {
        const unsigned long long vm = __ballot(ok);
        if (t == 0) nvalidS = __popcll(vm);        // asc d2 -> popcount == prefix
    }
    __syncthreads();
    const int nvalid = nvalidS;

    // ======== phase 2: h1 = relu(g + rel @ W1b + b1), IN PLACE over gs ======
    {
        const int c0 = (t & 15) * 4, n0 = (t >> 4) * 4;
        float rr[4][3];
        #pragma unroll
        for (int ni = 0; ni < 4; ++ni) {
            const int j = selj[n0 + ni];
            rr[ni][0] = pos[j * 3 + 0] - xi;
            rr[ni][1] = pos[j * 3 + 1] - yi;
            rr[ni][2] = pos[j * 3 + 2] - zi;
        }
        float w1b[3][4], bb[4];
        #pragma unroll
        for (int ci = 0; ci < 4; ++ci) {
            w1b[0][ci] = W1[4096 + c0 + ci];
            w1b[1][ci] = W1[4160 + c0 + ci];
            w1b[2][ci] = W1[4224 + c0 + ci];
            bb[ci]     = b1[c0 + ci];
        }
        #pragma unroll
        for (int ni = 0; ni < 4; ++ni) {
            const int n = n0 + ni;
            const float4 gv = *(const float4*)&gs[n][c0];
            float4 hv;
            #pragma unroll
            for (int ci = 0; ci < 4; ++ci) {
                float a = (&gv.x)[ci];             // == full ascending-k sum
                a = __fmaf_rn(rr[ni][0], w1b[0][ci], a);
                a = __fmaf_rn(rr[ni][1], w1b[1][ci], a);
                a = __fmaf_rn(rr[ni][2], w1b[2][ci], a);
                a = fmaxf(a + bb[ci], 0.0f);
                (&hv.x)[ci] = (n < nvalid) ? a : 0.0f;
            }
            *(float4*)&gs[n][c0] = hv;             // in-place h1
        }
    }
    __syncthreads();

    // ======== phase 3: h2 = relu(h1 @ W2 + b2); masked max over n ==========
    // Channel-split (two 4-ch halves), 2-row W2 tile, float2 h1 reads; the
    // per-output FMA chain runs cc = 0..63 strictly ascending -> bit-exact.
    {
        const float (*h1)[68] = gs;
        const int c4 = (t & 15) * 4;
        const int nb = (t >> 4) * 4;
        #pragma unroll
        for (int half = 0; half < 2; ++half) {
            const int ch0 = half * 64 + c4;
            float acc[4][4];
            #pragma unroll
            for (int ni = 0; ni < 4; ++ni)
                #pragma unroll
                for (int k = 0; k < 4; ++k) acc[ni][k] = 0.0f;

            #pragma unroll 2
            for (int ccb = 0; ccb < 16; ++ccb) {
                #pragma unroll
                for (int pr = 0; pr < 2; ++pr) {   // cc = ccb*4 + pr*2 + {0,1}
                    const int cc0 = ccb * 4 + pr * 2;
                    const float4 wt0 = *(const float4*)&W2[(cc0 + 0) * 128 + ch0];
                    const float4 wt1 = *(const float4*)&W2[(cc0 + 1) * 128 + ch0];
                    #pragma unroll
                    for (int ni = 0; ni < 4; ++ni) {
                        const float2 av = *(const float2*)&h1[nb + ni][cc0];
                        acc[ni][0] = __fmaf_rn(av.x, wt0.x, acc[ni][0]);
                        acc[ni][1] = __fmaf_rn(av.x, wt0.y, acc[ni][1]);
                        acc[ni][2] = __fmaf_rn(av.x, wt0.z, acc[ni][2]);
                        acc[ni][3] = __fmaf_rn(av.x, wt0.w, acc[ni][3]);
                        acc[ni][0] = __fmaf_rn(av.y, wt1.x, acc[ni][0]);
                        acc[ni][1] = __fmaf_rn(av.y, wt1.y, acc[ni][1]);
                        acc[ni][2] = __fmaf_rn(av.y, wt1.z, acc[ni][2]);
                        acc[ni][3] = __fmaf_rn(av.y, wt1.w, acc[ni][3]);
                    }
                }
            }
            float m4v[4];
            #pragma unroll
            for (int k = 0; k < 4; ++k) {
                const float bb = b2[ch0 + k];
                float mm = 0.0f;  // relu floor; valid set nonempty (self)
                #pragma unroll
                for (int ni = 0; ni < 4; ++ni)
                    if (nb + ni < nvalid) mm = fmaxf(mm, acc[ni][k] + bb);
                m4v[k] = mm;
            }
            #pragma unroll
            for (int k = 0; k < 4; ++k) {          // exact max-reduce over n-groups
                float v = m4v[k];
                v = fmaxf(v, __shfl_down(v, 32));
                v = fmaxf(v, __shfl_down(v, 16));
                m4v[k] = v;
            }
            if ((t & 63) < 16) {
                #pragma unroll
                for (int k = 0; k < 4; ++k) pmw[w][ch0 + k] = m4v[k];
            }
        }
    }
    __syncthreads();

    if (t < 128)
        aggS[t] = fmaxf(fmaxf(pmw[0][t], pmw[1][t]),
                        fmaxf(pmw[2][t], pmw[3][t]));
    __syncthreads();

    // ======== phase 4: out[i][t] = relu(aggS . Wg[:,t] + bg[t]) ============
    {
        float acc = 0.0f;
        #pragma unroll 8
        for (int k = 0; k < 128; ++k)
            acc = __fmaf_rn(aggS[k], Wg[k * 256 + t], acc);
        out[i * 256 + t] = fmaxf(acc + bg[t], 0.0f);
    }
}

// ---------------------------------------------------------------------------
extern "C" void kernel_launch(void* const* d_in, const int* in_sizes, int n_in,
                              void* d_out, int out_size, void* d_ws, size_t ws_size,
                              hipStream_t stream) {
    const float* x   = (const float*)d_in[0];
    const float* pos = (const float*)d_in[1];
    // d_in[2] = batch (all zeros) — unused
    const float* W1 = (const float*)d_in[3];
    const float* b1 = (const float*)d_in[4];
    const float* W2 = (const float*)d_in[5];
    const float* b2 = (const float*)d_in[6];
    const float* Wg = (const float*)d_in[7];
    const float* bg = (const float*)d_in[8];
    float* out = (float*)d_out;

    float* g = (float*)d_ws;   // 8192*64 floats = 2 MB, fully written by k_g

    k_g<<<N_PTS / 32, 256, 0, stream>>>(x, W1, g);
    k_sel<<<N_PTS, 256, 0, stream>>>(pos, out);
    k_mlp<<<N_PTS, 256, 0, stream>>>(g, pos, W1, b1, W2, b2, Wg, bg, out);
}